// Round 13
// baseline (301.880 us; speedup 1.0000x reference)
//
#include <hip/hip_runtime.h>
#include <hip/hip_bf16.h>

#define NN 25000
#define EE 200000
#define HH 64
#define LL 3
#define NB 98   // ceil(NN/256)
#define NCG 18

typedef __bf16 bf16x8 __attribute__((ext_vector_type(8)));
typedef float f32x4 __attribute__((ext_vector_type(4)));

__device__ __forceinline__ bf16x8 cvt8(float4 a, float4 b) {
    bf16x8 r;
    r[0] = (__bf16)a.x; r[1] = (__bf16)a.y; r[2] = (__bf16)a.z; r[3] = (__bf16)a.w;
    r[4] = (__bf16)b.x; r[5] = (__bf16)b.y; r[6] = (__bf16)b.z; r[7] = (__bf16)b.w;
    return r;
}

// packed B-fragment layout: [layer][cg(18)][cb(4)][lane(64)][8] bf16
// cg 0-5: [Wn_self;Wn_msg;Wn_edge]; cg 6-13: Wfc rows 0-255; cg 14-17: [We_self;We_nbr]
__device__ __forceinline__ bf16x8 load_bfrag(const __bf16* __restrict__ packw,
                                             int layer, int cg, int cb, int lane) {
    const __bf16* p = packw + ((((size_t)(layer * NCG + cg)) * 4 + cb) * 64 + lane) * 8;
    return *reinterpret_cast<const bf16x8*>(p);
}

__global__ void k_zero(int* __restrict__ p) {
    int i = blockIdx.x * 256 + threadIdx.x;
    if (i < NN) p[i] = 0;
}

__global__ void k_hist(const int* __restrict__ trg, int* __restrict__ count) {
    int e = blockIdx.x * 256 + threadIdx.x;
    if (e < EE) atomicAdd(&count[trg[e]], 1);
}

__global__ void __launch_bounds__(256) k_bsum(const int* __restrict__ count,
                                              int* __restrict__ btot) {
    int i = blockIdx.x * 256 + threadIdx.x;
    int v = (i < NN) ? count[i] : 0;
#pragma unroll
    for (int o = 1; o < 64; o <<= 1) v += __shfl_xor(v, o);
    __shared__ int l[4];
    if ((threadIdx.x & 63) == 0) l[threadIdx.x >> 6] = v;
    __syncthreads();
    if (threadIdx.x == 0) btot[blockIdx.x] = l[0] + l[1] + l[2] + l[3];
}

__global__ void k_bscan(const int* __restrict__ btot, int* __restrict__ bbase) {
    __shared__ int l[128];
    int t = threadIdx.x;
    int v = (t < NB) ? btot[t] : 0;
    l[t] = v;
    __syncthreads();
    for (int o = 1; o < 128; o <<= 1) {
        int u = (t >= o) ? l[t - o] : 0;
        __syncthreads();
        l[t] += u;
        __syncthreads();
    }
    if (t < NB) bbase[t] = l[t] - v;  // exclusive
}

__global__ void __launch_bounds__(256) k_apply(const int* __restrict__ count,
                                               const int* __restrict__ bbase,
                                               int* __restrict__ offs,
                                               int* __restrict__ cursor) {
    __shared__ int l[256];
    int t = threadIdx.x;
    int i = blockIdx.x * 256 + t;
    int v = (i < NN) ? count[i] : 0;
    l[t] = v;
    __syncthreads();
    for (int o = 1; o < 256; o <<= 1) {
        int u = (t >= o) ? l[t - o] : 0;
        __syncthreads();
        l[t] += u;
        __syncthreads();
    }
    int ex = bbase[blockIdx.x] + l[t] - v;
    if (i < NN) { offs[i] = ex; cursor[i] = ex; }
    if (i == NN - 1) offs[NN] = ex + v;
}

// fill CSR + permutation metadata: slot p holds edge inc[p];
// pos_of[e] = p, src_p[p] = e>>3, tv_p[p] = trg[e]
__global__ void k_fill(const int* __restrict__ trg, int* __restrict__ cursor,
                       int* __restrict__ inc, int* __restrict__ pos_of,
                       int* __restrict__ src_p, int* __restrict__ tv_p) {
    int e = blockIdx.x * 256 + threadIdx.x;
    if (e < EE) {
        int tr = trg[e];
        int pos = atomicAdd(&cursor[tr], 1);
        inc[pos] = e;
        pos_of[e] = pos;
        src_p[pos] = e >> 3;
        tv_p[pos] = tr;
    }
}

// ef_in (f32, edge order) -> bf16 CSR order (scattered full-row writes)
__global__ void __launch_bounds__(256) k_cvt0(
        const float* __restrict__ ef, const int* __restrict__ pos_of,
        __bf16* __restrict__ out) {
    int idx = blockIdx.x * 256 + threadIdx.x;   // EE*8 threads
    int e = idx >> 3, t = idx & 7;
    const float* r = ef + (size_t)e * HH + t * 8;
    float4 a0 = *(const float4*)r, a1 = *(const float4*)(r + 4);
    int pos = pos_of[e];
    *(bf16x8*)(out + (size_t)pos * HH + t * 8) = cvt8(a0, a1);
}

// pack weights into MFMA B-fragment layout (bf16)
__global__ void k_pack(const float* __restrict__ Wn_self, const float* __restrict__ Wn_msg,
                       const float* __restrict__ Wn_edge, const float* __restrict__ Wfc,
                       const float* __restrict__ We_self, const float* __restrict__ We_nbr,
                       __bf16* __restrict__ packw) {
    int idx = blockIdx.x * 256 + threadIdx.x;
    if (idx >= 3 * NCG * 4 * 64 * 8) return;
    int i  = idx & 7;
    int l  = (idx >> 3) & 63;
    int cb = (idx >> 9) & 3;
    int cgl = idx >> 11;          // layer*NCG + cg
    int layer = cgl / NCG;
    int cg = cgl % NCG;
    int col = cb * 16 + (l & 15);
    int krow = 8 * (l >> 4) + i;  // within 32-row chunk
    const float* M;
    int row;
    if (cg < 6) {
        const float* mats[3] = {Wn_self, Wn_msg, Wn_edge};
        M = mats[cg >> 1] + (size_t)layer * HH * HH;
        row = (cg & 1) * 32 + krow;
    } else if (cg < 14) {
        M = Wfc + (size_t)layer * 257 * HH;
        row = (cg - 6) * 32 + krow;
    } else {
        M = (((cg - 14) >> 1) == 0 ? We_self : We_nbr) + (size_t)layer * HH * HH;
        row = ((cg - 14) & 1) * 32 + krow;
    }
    packw[idx] = (__bf16)M[(size_t)row * HH + col];
}

// segment-sum aggregation: wave per node v; ebuf rows [offs[v],offs[v+1]) are
// CONTIGUOUS (CSR order) -> pure streaming; x rows gathered via src_p (node-sized, L2).
// XF32: x is f32 (layer 0, no relu); else bf16 + relu.
template<bool XF32>
__global__ void __launch_bounds__(256) k_agg(
        const void* __restrict__ xp, const __bf16* __restrict__ ebuf,
        const int* __restrict__ offs, const int* __restrict__ src_p,
        float* __restrict__ aggx, float* __restrict__ agge) {
    const float*  xf = (const float*)xp;
    const __bf16* xh = (const __bf16*)xp;
    int wave = threadIdx.x >> 6, lane = threadIdx.x & 63;
    int v = blockIdx.x * 4 + wave;
    int s = offs[v], en = offs[v + 1];
    int g = lane >> 3, t = lane & 7;
    float ax[8] = {0,0,0,0,0,0,0,0};
    float ae[8] = {0,0,0,0,0,0,0,0};
    for (int p = s + g; p < en; p += 8) {
        int u = src_p[p];
        bf16x8 f = *(const bf16x8*)(ebuf + (size_t)p * HH + t * 8);
        float xv[8];
        if constexpr (XF32) {
            const float* xr = xf + (size_t)u * HH + t * 8;
            float4 x0 = *(const float4*)xr, x1 = *(const float4*)(xr + 4);
            xv[0]=x0.x; xv[1]=x0.y; xv[2]=x0.z; xv[3]=x0.w;
            xv[4]=x1.x; xv[5]=x1.y; xv[6]=x1.z; xv[7]=x1.w;
        } else {
            bf16x8 xb = *(const bf16x8*)(xh + (size_t)u * HH + t * 8);
#pragma unroll
            for (int k = 0; k < 8; k++) xv[k] = fmaxf((float)xb[k], 0.f);
        }
#pragma unroll
        for (int k = 0; k < 8; k++) {
            ax[k] += xv[k];
            ae[k] += (float)f[k];
        }
    }
#pragma unroll
    for (int k = 0; k < 8; k++) {
        ax[k] += __shfl_xor(ax[k], 8); ax[k] += __shfl_xor(ax[k], 16); ax[k] += __shfl_xor(ax[k], 32);
        ae[k] += __shfl_xor(ae[k], 8); ae[k] += __shfl_xor(ae[k], 16); ae[k] += __shfl_xor(ae[k], 32);
    }
    if (g == 0) {
        *(float4*)(aggx + (size_t)v * HH + t * 8)     = make_float4(ax[0], ax[1], ax[2], ax[3]);
        *(float4*)(aggx + (size_t)v * HH + t * 8 + 4) = make_float4(ax[4], ax[5], ax[6], ax[7]);
        *(float4*)(agge + (size_t)v * HH + t * 8)     = make_float4(ae[0], ae[1], ae[2], ae[3]);
        *(float4*)(agge + (size_t)v * HH + t * 8 + 4) = make_float4(ae[4], ae[5], ae[6], ae[7]);
    }
}

// segment-sum of efc (CSR order, streaming) -> AGG (f32, node-sized)
__global__ void __launch_bounds__(256) k_aggef(
        const __bf16* __restrict__ efc, const int* __restrict__ offs,
        float* __restrict__ AGG) {
    int wave = threadIdx.x >> 6, lane = threadIdx.x & 63;
    int v = blockIdx.x * 4 + wave;
    int s = offs[v], en = offs[v + 1];
    int g = lane >> 3, t = lane & 7;
    float ae[8] = {0,0,0,0,0,0,0,0};
    for (int p = s + g; p < en; p += 8) {
        bf16x8 f = *(const bf16x8*)(efc + (size_t)p * HH + t * 8);
#pragma unroll
        for (int k = 0; k < 8; k++) ae[k] += (float)f[k];
    }
#pragma unroll
    for (int k = 0; k < 8; k++) {
        ae[k] += __shfl_xor(ae[k], 8); ae[k] += __shfl_xor(ae[k], 16); ae[k] += __shfl_xor(ae[k], 32);
    }
    if (g == 0) {
        *(float4*)(AGG + (size_t)v * HH + t * 8)     = make_float4(ae[0], ae[1], ae[2], ae[3]);
        *(float4*)(AGG + (size_t)v * HH + t * 8 + 4) = make_float4(ae[4], ae[5], ae[6], ae[7]);
    }
}

// x_new(bf16) = [relu?(x) | aggx | agge] @ [Wn_self;Wn_msg;Wn_edge] + bn (pre-relu out)
template<bool XF32>
__global__ void __launch_bounds__(256) k_node(
        const void* __restrict__ xp, const float* __restrict__ aggx,
        const float* __restrict__ agge, const __bf16* __restrict__ packw,
        const float* __restrict__ bn, __bf16* __restrict__ xout, int layer) {
    const float*  xf = (const float*)xp;
    const __bf16* xh = (const __bf16*)xp;
    int wave = threadIdx.x >> 6, lane = threadIdx.x & 63;
    int tile = blockIdx.x * 4 + wave;
    if (tile * 16 >= NN) return;
    int r16 = lane & 15, hi = lane >> 4;
    int row = tile * 16 + r16;
    int rowc = row < NN ? row : NN - 1;
    f32x4 acc[4] = {{0,0,0,0},{0,0,0,0},{0,0,0,0},{0,0,0,0}};
#pragma unroll
    for (int c = 0; c < 6; c++) {
        int seg = c >> 1;
        bf16x8 a;
        if (seg == 0) {
            if constexpr (XF32) {
                const float4* p = (const float4*)(xf + (size_t)rowc * HH + (c & 1) * 32 + hi * 8);
                a = cvt8(p[0], p[1]);   // layer 0: no relu
            } else {
                bf16x8 v = *(const bf16x8*)(xh + (size_t)rowc * HH + (c & 1) * 32 + hi * 8);
#pragma unroll
                for (int k = 0; k < 8; k++) a[k] = (__bf16)fmaxf((float)v[k], 0.f);  // relu
            }
        } else {
            const float* base = (seg == 1 ? aggx : agge) + (size_t)rowc * HH;
            const float4* p = (const float4*)(base + (c & 1) * 32 + hi * 8);
            a = cvt8(p[0], p[1]);
        }
#pragma unroll
        for (int cb = 0; cb < 4; cb++) {
            bf16x8 b = load_bfrag(packw, layer, c, cb, lane);
            acc[cb] = __builtin_amdgcn_mfma_f32_16x16x32_bf16(a, b, acc[cb], 0, 0, 0);
        }
    }
#pragma unroll
    for (int cb = 0; cb < 4; cb++) {
        int col = cb * 16 + r16;
        float bias = bn[layer * HH + col];
#pragma unroll
        for (int r = 0; r < 4; r++) {
            int orow = tile * 16 + hi * 4 + r;
            if (orow < NN) xout[(size_t)orow * HH + col] = (__bf16)(acc[cb][r] + bias);
        }
    }
}

// ef_out(bf16, CSR order) = [ef | xs | xt | |xs-xt| | sim] @ Wfc + bfc  (16 slots/wave)
__global__ void __launch_bounds__(256) k_fc(
        const __bf16* __restrict__ efp, const __bf16* __restrict__ xn,
        const int* __restrict__ src_p, const int* __restrict__ tv_p,
        const __bf16* __restrict__ packw,
        const float* __restrict__ Wfc, const float* __restrict__ bfc,
        __bf16* __restrict__ efout, int layer) {
    int wave = threadIdx.x >> 6, lane = threadIdx.x & 63;
    int tile = blockIdx.x * 4 + wave;
    int r16 = lane & 15, hi = lane >> 4;
    int p = tile * 16 + r16;
    int srcn = src_p[p];
    int tn = tv_p[p];
    f32x4 acc[4] = {{0,0,0,0},{0,0,0,0},{0,0,0,0},{0,0,0,0}};
    float xsv[16], xtv[16];
#pragma unroll
    for (int c = 0; c < 8; c++) {
        int half = c & 1;
        bf16x8 a;
        if (c < 2) {
            a = *(const bf16x8*)(efp + (size_t)p * HH + half * 32 + hi * 8);
        } else if (c < 4) {
            a = *(const bf16x8*)(xn + (size_t)srcn * HH + half * 32 + hi * 8);
#pragma unroll
            for (int k = 0; k < 8; k++) xsv[half * 8 + k] = (float)a[k];
        } else if (c < 6) {
            a = *(const bf16x8*)(xn + (size_t)tn * HH + half * 32 + hi * 8);
#pragma unroll
            for (int k = 0; k < 8; k++) xtv[half * 8 + k] = (float)a[k];
        } else {
#pragma unroll
            for (int k = 0; k < 8; k++)
                a[k] = (__bf16)fabsf(xsv[half * 8 + k] - xtv[half * 8 + k]);
        }
#pragma unroll
        for (int cb = 0; cb < 4; cb++) {
            bf16x8 b = load_bfrag(packw, layer, 6 + c, cb, lane);
            acc[cb] = __builtin_amdgcn_mfma_f32_16x16x32_bf16(a, b, acc[cb], 0, 0, 0);
        }
    }
    float dp = 0.f, nx2 = 0.f, nt2 = 0.f;
#pragma unroll
    for (int j = 0; j < 16; j++) {
        dp  += xsv[j] * xtv[j];
        nx2 += xsv[j] * xsv[j];
        nt2 += xtv[j] * xtv[j];
    }
    dp  += __shfl_xor(dp, 16);  dp  += __shfl_xor(dp, 32);
    nx2 += __shfl_xor(nx2, 16); nx2 += __shfl_xor(nx2, 32);
    nt2 += __shfl_xor(nt2, 16); nt2 += __shfl_xor(nt2, 32);
    float sim = dp / fmaxf(sqrtf(nx2 * nt2), 1e-8f);
    float simr[4];
#pragma unroll
    for (int r = 0; r < 4; r++) simr[r] = __shfl(sim, hi * 4 + r);
    const float* wlast = Wfc + ((size_t)layer * 257 + 256) * HH;  // row 256 (sim)
#pragma unroll
    for (int cb = 0; cb < 4; cb++) {
        int col = cb * 16 + r16;
        float wl = wlast[col];
        float bias = bfc[layer * HH + col];
#pragma unroll
        for (int r = 0; r < 4; r++) {
            efout[(size_t)(tile * 16 + hi * 4 + r) * HH + col] =
                (__bf16)(acc[cb][r] + simr[r] * wl + bias);
        }
    }
}

// edge update (CSR order): out = [efc | AGG[src_p[p]]] @ [We_self;We_nbr] + be
// LAST: scatter f32 rows to d_out[inc[p]]; else stream bf16 to ebuf_next[p].
template<int LAST>
__global__ void __launch_bounds__(256) k_edge(
        const __bf16* __restrict__ efc, const float* __restrict__ AGG,
        const int* __restrict__ src_p, const int* __restrict__ inc,
        const __bf16* __restrict__ packw, const float* __restrict__ be,
        __bf16* __restrict__ out16, float* __restrict__ out32, int layer) {
    int wave = threadIdx.x >> 6, lane = threadIdx.x & 63;
    int tile = blockIdx.x * 4 + wave;
    int r16 = lane & 15, hi = lane >> 4;
    int p = tile * 16 + r16;
    int srcn = src_p[p];
    f32x4 acc[4] = {{0,0,0,0},{0,0,0,0},{0,0,0,0},{0,0,0,0}};
#pragma unroll
    for (int c = 0; c < 4; c++) {
        bf16x8 a;
        if (c < 2) {
            a = *(const bf16x8*)(efc + (size_t)p * HH + (c & 1) * 32 + hi * 8);
        } else {
            const float4* q = (const float4*)(AGG + (size_t)srcn * HH + (c & 1) * 32 + hi * 8);
            a = cvt8(q[0], q[1]);
        }
#pragma unroll
        for (int cb = 0; cb < 4; cb++) {
            bf16x8 b = load_bfrag(packw, layer, 14 + c, cb, lane);
            acc[cb] = __builtin_amdgcn_mfma_f32_16x16x32_bf16(a, b, acc[cb], 0, 0, 0);
        }
    }
#pragma unroll
    for (int cb = 0; cb < 4; cb++) {
        int col = cb * 16 + r16;
        float bias = be[layer * HH + col];
#pragma unroll
        for (int r = 0; r < 4; r++) {
            int q = tile * 16 + hi * 4 + r;
            float val = acc[cb][r] + bias;
            if (LAST) {
                int er = inc[q];
                out32[(size_t)er * HH + col] = val;
            } else {
                out16[(size_t)q * HH + col] = (__bf16)val;
            }
        }
    }
}

extern "C" void kernel_launch(void* const* d_in, const int* in_sizes, int n_in,
                              void* d_out, int out_size, void* d_ws, size_t ws_size,
                              hipStream_t stream) {
    const float* x_in    = (const float*)d_in[0];
    const float* ef_in   = (const float*)d_in[1];
    const float* Wn_self = (const float*)d_in[2];
    const float* Wn_msg  = (const float*)d_in[3];
    const float* Wn_edge = (const float*)d_in[4];
    const float* bn      = (const float*)d_in[5];
    const float* Wfc     = (const float*)d_in[6];
    const float* bfc     = (const float*)d_in[7];
    const float* We_self = (const float*)d_in[8];
    const float* We_nbr  = (const float*)d_in[9];
    const float* be      = (const float*)d_in[10];
    const int*   trg     = (const int*)d_in[12];

    size_t off = 0;
    char* w = (char*)d_ws;
    auto alloc = [&](size_t bytes) -> char* {
        char* p = w + off;
        off += (bytes + 255) & ~(size_t)255;
        return p;
    };
    int*    count  = (int*)alloc((size_t)NN * 4);
    int*    offs   = (int*)alloc((size_t)(NN + 1) * 4);
    int*    cursor = (int*)alloc((size_t)NN * 4);
    int*    inc    = (int*)alloc((size_t)EE * 4);
    int*    pos_of = (int*)alloc((size_t)EE * 4);
    int*    src_p  = (int*)alloc((size_t)EE * 4);
    int*    tv_p   = (int*)alloc((size_t)EE * 4);
    int*    btot   = (int*)alloc((size_t)NB * 4);
    int*    bbase  = (int*)alloc((size_t)NB * 4);
    __bf16* packw  = (__bf16*)alloc((size_t)3 * NCG * 4 * 64 * 8 * 2);
    float*  aggx   = (float*)alloc((size_t)NN * HH * 4);
    float*  agge   = (float*)alloc((size_t)NN * HH * 4);
    float*  AGG    = (float*)alloc((size_t)NN * HH * 4);
    __bf16* xA     = (__bf16*)alloc((size_t)NN * HH * 2);
    __bf16* xB     = (__bf16*)alloc((size_t)NN * HH * 2);
    __bf16* ebA    = (__bf16*)alloc((size_t)EE * HH * 2);
    __bf16* ebB    = (__bf16*)alloc((size_t)EE * HH * 2);
    __bf16* efc16  = (__bf16*)alloc((size_t)EE * HH * 2);

    k_zero<<<(NN + 255) / 256, 256, 0, stream>>>(count);
    k_hist<<<(EE + 255) / 256, 256, 0, stream>>>(trg, count);
    k_bsum<<<NB, 256, 0, stream>>>(count, btot);
    k_bscan<<<1, 128, 0, stream>>>(btot, bbase);
    k_apply<<<NB, 256, 0, stream>>>(count, bbase, offs, cursor);
    k_fill<<<(EE + 255) / 256, 256, 0, stream>>>(trg, cursor, inc, pos_of, src_p, tv_p);
    k_pack<<<(3 * NCG * 4 * 64 * 8 + 255) / 256, 256, 0, stream>>>(
        Wn_self, Wn_msg, Wn_edge, Wfc, We_self, We_nbr, packw);
    k_cvt0<<<EE * 8 / 256, 256, 0, stream>>>(ef_in, pos_of, ebA);

    __bf16* xbuf[3] = {xA, xB, xA};
    int ntile = (NN + 15) / 16;
    int nodeblk = (ntile + 3) / 4;

    // ---- layer 0 (x f32, no relu) ----
    k_agg<true><<<NN / 4, 256, 0, stream>>>(x_in, ebA, offs, src_p, aggx, agge);
    k_node<true><<<nodeblk, 256, 0, stream>>>(x_in, aggx, agge, packw, bn, xbuf[0], 0);
    k_fc<<<EE / 64, 256, 0, stream>>>(ebA, xbuf[0], src_p, tv_p, packw, Wfc, bfc, efc16, 0);
    k_aggef<<<NN / 4, 256, 0, stream>>>(efc16, offs, AGG);
    k_edge<0><<<EE / 64, 256, 0, stream>>>(efc16, AGG, src_p, inc, packw, be,
                                           ebB, (float*)d_out, 0);
    // ---- layers 1..2 ----
    const __bf16* efprev = ebB;
    __bf16* enextbuf[2] = {ebA, ebB};
    for (int i = 1; i < LL; i++) {
        k_agg<false><<<NN / 4, 256, 0, stream>>>(xbuf[i - 1], efprev, offs, src_p, aggx, agge);
        k_node<false><<<nodeblk, 256, 0, stream>>>(xbuf[i - 1], aggx, agge, packw, bn, xbuf[i], i);
        k_fc<<<EE / 64, 256, 0, stream>>>(efprev, xbuf[i], src_p, tv_p, packw, Wfc, bfc, efc16, i);
        k_aggef<<<NN / 4, 256, 0, stream>>>(efc16, offs, AGG);
        __bf16* enext = enextbuf[(i + 1) & 1];
        if (i < LL - 1)
            k_edge<0><<<EE / 64, 256, 0, stream>>>(efc16, AGG, src_p, inc, packw, be,
                                                   enext, (float*)d_out, i);
        else
            k_edge<1><<<EE / 64, 256, 0, stream>>>(efc16, AGG, src_p, inc, packw, be,
                                                   enext, (float*)d_out, i);
        efprev = enext;
    }
}

// Round 14
// 263.719 us; speedup vs baseline: 1.1447x; 1.1447x over previous
//
#include <hip/hip_runtime.h>
#include <hip/hip_bf16.h>

#define NN 25000
#define EE 200000
#define HH 64
#define LL 3
#define NB 98   // ceil(NN/256)
#define NCG 18

typedef __bf16 bf16x8 __attribute__((ext_vector_type(8)));
typedef float f32x4 __attribute__((ext_vector_type(4)));

__device__ __forceinline__ bf16x8 cvt8(float4 a, float4 b) {
    bf16x8 r;
    r[0] = (__bf16)a.x; r[1] = (__bf16)a.y; r[2] = (__bf16)a.z; r[3] = (__bf16)a.w;
    r[4] = (__bf16)b.x; r[5] = (__bf16)b.y; r[6] = (__bf16)b.z; r[7] = (__bf16)b.w;
    return r;
}

// packed B-fragment layout: [layer][cg(18)][cb(4)][lane(64)][8] bf16
// cg 0-5: [Wn_self;Wn_msg;Wn_edge]; cg 6-13: Wfc rows 0-255; cg 14-17: [We_self;We_nbr]
__device__ __forceinline__ bf16x8 load_bfrag(const __bf16* __restrict__ packw,
                                             int layer, int cg, int cb, int lane) {
    const __bf16* p = packw + ((((size_t)(layer * NCG + cg)) * 4 + cb) * 64 + lane) * 8;
    return *reinterpret_cast<const bf16x8*>(p);
}

__global__ void k_zero(int* __restrict__ p) {
    int i = blockIdx.x * 256 + threadIdx.x;
    if (i < NN) p[i] = 0;
}

__global__ void k_hist(const int* __restrict__ trg, int* __restrict__ count) {
    int e = blockIdx.x * 256 + threadIdx.x;
    if (e < EE) atomicAdd(&count[trg[e]], 1);
}

__global__ void __launch_bounds__(256) k_bsum(const int* __restrict__ count,
                                              int* __restrict__ btot) {
    int i = blockIdx.x * 256 + threadIdx.x;
    int v = (i < NN) ? count[i] : 0;
#pragma unroll
    for (int o = 1; o < 64; o <<= 1) v += __shfl_xor(v, o);
    __shared__ int l[4];
    if ((threadIdx.x & 63) == 0) l[threadIdx.x >> 6] = v;
    __syncthreads();
    if (threadIdx.x == 0) btot[blockIdx.x] = l[0] + l[1] + l[2] + l[3];
}

__global__ void k_bscan(const int* __restrict__ btot, int* __restrict__ bbase) {
    __shared__ int l[128];
    int t = threadIdx.x;
    int v = (t < NB) ? btot[t] : 0;
    l[t] = v;
    __syncthreads();
    for (int o = 1; o < 128; o <<= 1) {
        int u = (t >= o) ? l[t - o] : 0;
        __syncthreads();
        l[t] += u;
        __syncthreads();
    }
    if (t < NB) bbase[t] = l[t] - v;  // exclusive
}

__global__ void __launch_bounds__(256) k_apply(const int* __restrict__ count,
                                               const int* __restrict__ bbase,
                                               int* __restrict__ offs,
                                               int* __restrict__ cursor) {
    __shared__ int l[256];
    int t = threadIdx.x;
    int i = blockIdx.x * 256 + t;
    int v = (i < NN) ? count[i] : 0;
    l[t] = v;
    __syncthreads();
    for (int o = 1; o < 256; o <<= 1) {
        int u = (t >= o) ? l[t - o] : 0;
        __syncthreads();
        l[t] += u;
        __syncthreads();
    }
    int ex = bbase[blockIdx.x] + l[t] - v;
    if (i < NN) { offs[i] = ex; cursor[i] = ex; }
    if (i == NN - 1) offs[NN] = ex + v;
}

__global__ void k_fill(const int* __restrict__ trg, int* __restrict__ cursor,
                       int* __restrict__ inc) {
    int e = blockIdx.x * 256 + threadIdx.x;
    if (e < EE) {
        int pos = atomicAdd(&cursor[trg[e]], 1);
        inc[pos] = e;
    }
}

// pack weights into MFMA B-fragment layout (bf16)
__global__ void k_pack(const float* __restrict__ Wn_self, const float* __restrict__ Wn_msg,
                       const float* __restrict__ Wn_edge, const float* __restrict__ Wfc,
                       const float* __restrict__ We_self, const float* __restrict__ We_nbr,
                       __bf16* __restrict__ packw) {
    int idx = blockIdx.x * 256 + threadIdx.x;
    if (idx >= 3 * NCG * 4 * 64 * 8) return;
    int i  = idx & 7;
    int l  = (idx >> 3) & 63;
    int cb = (idx >> 9) & 3;
    int cgl = idx >> 11;          // layer*NCG + cg
    int layer = cgl / NCG;
    int cg = cgl % NCG;
    int col = cb * 16 + (l & 15);
    int krow = 8 * (l >> 4) + i;  // within 32-row chunk
    const float* M;
    int row;
    if (cg < 6) {
        const float* mats[3] = {Wn_self, Wn_msg, Wn_edge};
        M = mats[cg >> 1] + (size_t)layer * HH * HH;
        row = (cg & 1) * 32 + krow;
    } else if (cg < 14) {
        M = Wfc + (size_t)layer * 257 * HH;
        row = (cg - 6) * 32 + krow;
    } else {
        M = (((cg - 14) >> 1) == 0 ? We_self : We_nbr) + (size_t)layer * HH * HH;
        row = ((cg - 14) & 1) * 32 + krow;
    }
    packw[idx] = (__bf16)M[(size_t)row * HH + col];
}

// wave per node; 8 edge slots (8 groups x 8 lanes).
// XF32/EF32: x / ef streams are f32 (layer 0) or bf16 (layers >0).
// dorelu is implied: layer>0 only (XF32 == !dorelu).
template<bool XF32, bool EF32>
__global__ void __launch_bounds__(256) k_agg_node(
        const void* __restrict__ xp, const void* __restrict__ efp,
        const int* __restrict__ offs, const int* __restrict__ inc,
        float* __restrict__ aggx, float* __restrict__ agge) {
    const float*  xf  = (const float*)xp;
    const __bf16* xh  = (const __bf16*)xp;
    const float*  eff = (const float*)efp;
    const __bf16* efh = (const __bf16*)efp;
    int wave = threadIdx.x >> 6, lane = threadIdx.x & 63;
    int v = blockIdx.x * 4 + wave;
    int s = offs[v], en = offs[v + 1];
    int deg = en - s;
    int g = lane >> 3, t = lane & 7;
    float ax[8] = {0,0,0,0,0,0,0,0};
    float ae[8] = {0,0,0,0,0,0,0,0};
    if (deg > 0) {
        int dm1 = deg - 1;
        int idx = inc[s + (lane < deg ? lane : dm1)];
        int nblk = (deg + 7) >> 3;
        if (nblk > 8) nblk = 8;
        for (int b = 0; b < nblk; b++) {      // wave-uniform trip count
            int j = b * 8 + g;
            int e0 = __shfl(idx, j < deg ? j : dm1);
            float w = (j < deg) ? 1.f : 0.f;
            float xv[8];
            if constexpr (XF32) {
                const float* xr = xf + (size_t)(e0 >> 3) * HH + t * 8;
                float4 x0 = *(const float4*)xr, x1 = *(const float4*)(xr + 4);
                xv[0]=x0.x; xv[1]=x0.y; xv[2]=x0.z; xv[3]=x0.w;
                xv[4]=x1.x; xv[5]=x1.y; xv[6]=x1.z; xv[7]=x1.w;
            } else {
                bf16x8 xb = *(const bf16x8*)(xh + (size_t)(e0 >> 3) * HH + t * 8);
#pragma unroll
                for (int k = 0; k < 8; k++) xv[k] = fmaxf((float)xb[k], 0.f);  // relu
            }
            float fv[8];
            if constexpr (EF32) {
                const float* fr = eff + (size_t)e0 * HH + t * 8;
                float4 f0 = *(const float4*)fr, f1 = *(const float4*)(fr + 4);
                fv[0]=f0.x; fv[1]=f0.y; fv[2]=f0.z; fv[3]=f0.w;
                fv[4]=f1.x; fv[5]=f1.y; fv[6]=f1.z; fv[7]=f1.w;
            } else {
                bf16x8 f = *(const bf16x8*)(efh + (size_t)e0 * HH + t * 8);
#pragma unroll
                for (int k = 0; k < 8; k++) fv[k] = (float)f[k];
            }
#pragma unroll
            for (int k = 0; k < 8; k++) {
                ax[k] += w * xv[k];
                ae[k] += w * fv[k];
            }
        }
        for (int j = 64 + g; j < deg; j += 8) {  // essentially never
            int e0 = inc[s + j];
            float xv[8];
            if constexpr (XF32) {
                const float* xr = xf + (size_t)(e0 >> 3) * HH + t * 8;
                float4 x0 = *(const float4*)xr, x1 = *(const float4*)(xr + 4);
                xv[0]=x0.x; xv[1]=x0.y; xv[2]=x0.z; xv[3]=x0.w;
                xv[4]=x1.x; xv[5]=x1.y; xv[6]=x1.z; xv[7]=x1.w;
            } else {
                bf16x8 xb = *(const bf16x8*)(xh + (size_t)(e0 >> 3) * HH + t * 8);
#pragma unroll
                for (int k = 0; k < 8; k++) xv[k] = fmaxf((float)xb[k], 0.f);
            }
            float fv[8];
            if constexpr (EF32) {
                const float* fr = eff + (size_t)e0 * HH + t * 8;
                float4 f0 = *(const float4*)fr, f1 = *(const float4*)(fr + 4);
                fv[0]=f0.x; fv[1]=f0.y; fv[2]=f0.z; fv[3]=f0.w;
                fv[4]=f1.x; fv[5]=f1.y; fv[6]=f1.z; fv[7]=f1.w;
            } else {
                bf16x8 f = *(const bf16x8*)(efh + (size_t)e0 * HH + t * 8);
#pragma unroll
                for (int k = 0; k < 8; k++) fv[k] = (float)f[k];
            }
#pragma unroll
            for (int k = 0; k < 8; k++) {
                ax[k] += xv[k];
                ae[k] += fv[k];
            }
        }
    }
#pragma unroll
    for (int k = 0; k < 8; k++) {
        ax[k] += __shfl_xor(ax[k], 8);
        ax[k] += __shfl_xor(ax[k], 16);
        ax[k] += __shfl_xor(ax[k], 32);
        ae[k] += __shfl_xor(ae[k], 8);
        ae[k] += __shfl_xor(ae[k], 16);
        ae[k] += __shfl_xor(ae[k], 32);
    }
    if (g == 0) {
        *(float4*)(aggx + (size_t)v * HH + t * 8)     = make_float4(ax[0], ax[1], ax[2], ax[3]);
        *(float4*)(aggx + (size_t)v * HH + t * 8 + 4) = make_float4(ax[4], ax[5], ax[6], ax[7]);
        *(float4*)(agge + (size_t)v * HH + t * 8)     = make_float4(ae[0], ae[1], ae[2], ae[3]);
        *(float4*)(agge + (size_t)v * HH + t * 8 + 4) = make_float4(ae[4], ae[5], ae[6], ae[7]);
    }
}

// x_new(bf16) = [relu?(x) | aggx | agge] @ [Wn_self;Wn_msg;Wn_edge] + bn (pre-relu out)
template<bool XF32>
__global__ void __launch_bounds__(256) k_node(
        const void* __restrict__ xp, const float* __restrict__ aggx,
        const float* __restrict__ agge, const __bf16* __restrict__ packw,
        const float* __restrict__ bn, __bf16* __restrict__ xout, int layer) {
    const float*  xf = (const float*)xp;
    const __bf16* xh = (const __bf16*)xp;
    int wave = threadIdx.x >> 6, lane = threadIdx.x & 63;
    int tile = blockIdx.x * 4 + wave;
    if (tile * 16 >= NN) return;
    int r16 = lane & 15, hi = lane >> 4;
    int row = tile * 16 + r16;
    int rowc = row < NN ? row : NN - 1;
    f32x4 acc[4] = {{0,0,0,0},{0,0,0,0},{0,0,0,0},{0,0,0,0}};
#pragma unroll
    for (int c = 0; c < 6; c++) {
        int seg = c >> 1;
        bf16x8 a;
        if (seg == 0) {
            if constexpr (XF32) {
                const float4* p = (const float4*)(xf + (size_t)rowc * HH + (c & 1) * 32 + hi * 8);
                a = cvt8(p[0], p[1]);   // layer 0: no relu
            } else {
                bf16x8 v = *(const bf16x8*)(xh + (size_t)rowc * HH + (c & 1) * 32 + hi * 8);
#pragma unroll
                for (int k = 0; k < 8; k++) a[k] = (__bf16)fmaxf((float)v[k], 0.f);  // relu
            }
        } else {
            const float* base = (seg == 1 ? aggx : agge) + (size_t)rowc * HH;
            const float4* p = (const float4*)(base + (c & 1) * 32 + hi * 8);
            a = cvt8(p[0], p[1]);
        }
#pragma unroll
        for (int cb = 0; cb < 4; cb++) {
            bf16x8 b = load_bfrag(packw, layer, c, cb, lane);
            acc[cb] = __builtin_amdgcn_mfma_f32_16x16x32_bf16(a, b, acc[cb], 0, 0, 0);
        }
    }
#pragma unroll
    for (int cb = 0; cb < 4; cb++) {
        int col = cb * 16 + r16;
        float bias = bn[layer * HH + col];
#pragma unroll
        for (int r = 0; r < 4; r++) {
            int orow = tile * 16 + hi * 4 + r;
            if (orow < NN) xout[(size_t)orow * HH + col] = (__bf16)(acc[cb][r] + bias);
        }
    }
}

// ef_out(bf16) = [ef_in | xs | xt | |xs-xt| | sim] @ Wfc + bfc  (sim fused, 16 edges/wave)
// xn is bf16; sim computed from bf16-rounded values (within tolerance).
template<bool EF32>
__global__ void __launch_bounds__(256) k_fc(
        const void* __restrict__ efp, const __bf16* __restrict__ xn,
        const int* __restrict__ trg, const __bf16* __restrict__ packw,
        const float* __restrict__ Wfc, const float* __restrict__ bfc,
        __bf16* __restrict__ efout, int layer) {
    const float*  eff = (const float*)efp;
    const __bf16* efh = (const __bf16*)efp;
    int wave = threadIdx.x >> 6, lane = threadIdx.x & 63;
    int tile = blockIdx.x * 4 + wave;
    int r16 = lane & 15, hi = lane >> 4;
    int e = tile * 16 + r16;
    int srcn = e >> 3;
    int tn = trg[e];
    f32x4 acc[4] = {{0,0,0,0},{0,0,0,0},{0,0,0,0},{0,0,0,0}};
    float xsv[16], xtv[16];
#pragma unroll
    for (int c = 0; c < 8; c++) {
        int half = c & 1;
        bf16x8 a;
        if (c < 2) {
            if constexpr (EF32) {
                const float4* p = (const float4*)(eff + (size_t)e * HH + half * 32 + hi * 8);
                a = cvt8(p[0], p[1]);
            } else {
                a = *(const bf16x8*)(efh + (size_t)e * HH + half * 32 + hi * 8);
            }
        } else if (c < 4) {
            a = *(const bf16x8*)(xn + (size_t)srcn * HH + half * 32 + hi * 8);
#pragma unroll
            for (int k = 0; k < 8; k++) xsv[half * 8 + k] = (float)a[k];
        } else if (c < 6) {
            a = *(const bf16x8*)(xn + (size_t)tn * HH + half * 32 + hi * 8);
#pragma unroll
            for (int k = 0; k < 8; k++) xtv[half * 8 + k] = (float)a[k];
        } else {
#pragma unroll
            for (int k = 0; k < 8; k++)
                a[k] = (__bf16)fabsf(xsv[half * 8 + k] - xtv[half * 8 + k]);
        }
#pragma unroll
        for (int cb = 0; cb < 4; cb++) {
            bf16x8 b = load_bfrag(packw, layer, 6 + c, cb, lane);
            acc[cb] = __builtin_amdgcn_mfma_f32_16x16x32_bf16(a, b, acc[cb], 0, 0, 0);
        }
    }
    float dp = 0.f, nx2 = 0.f, nt2 = 0.f;
#pragma unroll
    for (int j = 0; j < 16; j++) {
        dp  += xsv[j] * xtv[j];
        nx2 += xsv[j] * xsv[j];
        nt2 += xtv[j] * xtv[j];
    }
    dp  += __shfl_xor(dp, 16);  dp  += __shfl_xor(dp, 32);
    nx2 += __shfl_xor(nx2, 16); nx2 += __shfl_xor(nx2, 32);
    nt2 += __shfl_xor(nt2, 16); nt2 += __shfl_xor(nt2, 32);
    float sim = dp / fmaxf(sqrtf(nx2 * nt2), 1e-8f);
    float simr[4];
#pragma unroll
    for (int r = 0; r < 4; r++) simr[r] = __shfl(sim, hi * 4 + r);
    const float* wlast = Wfc + ((size_t)layer * 257 + 256) * HH;  // row 256 (sim)
#pragma unroll
    for (int cb = 0; cb < 4; cb++) {
        int col = cb * 16 + r16;
        float wl = wlast[col];
        float bias = bfc[layer * HH + col];
#pragma unroll
        for (int r = 0; r < 4; r++) {
            efout[(size_t)(tile * 16 + hi * 4 + r) * HH + col] =
                (__bf16)(acc[cb][r] + simr[r] * wl + bias);
        }
    }
}

// fused: phase 1 aggregates incoming efc for the block's 8 source nodes into LDS,
// phase 2: edge_out = [efc | aggef_lds[e>>3]] @ [We_self;We_nbr] + be
template<int LAST>
__global__ void __launch_bounds__(256) k_edgeout(
        const __bf16* __restrict__ efc, const int* __restrict__ offs,
        const int* __restrict__ inc, const __bf16* __restrict__ packw,
        const float* __restrict__ be, __bf16* __restrict__ out16,
        float* __restrict__ out32, int layer) {
    __shared__ float aggl[8][HH];
    int wave = threadIdx.x >> 6, lane = threadIdx.x & 63;
    int g = lane >> 3, t = lane & 7;
    // phase 1: 2 nodes per wave
#pragma unroll
    for (int q = 0; q < 2; q++) {
        int vloc = wave * 2 + q;
        int v = blockIdx.x * 8 + vloc;
        int s = offs[v], en = offs[v + 1];
        int deg = en - s;
        float a[8] = {0,0,0,0,0,0,0,0};
        if (deg > 0) {
            int dm1 = deg - 1;
            int idx = inc[s + (lane < deg ? lane : dm1)];
            int nblk = (deg + 7) >> 3;
            if (nblk > 8) nblk = 8;
            for (int b = 0; b < nblk; b++) {
                int j = b * 8 + g;
                int e0 = __shfl(idx, j < deg ? j : dm1);
                float w = (j < deg) ? 1.f : 0.f;
                bf16x8 f = *(const bf16x8*)(efc + (size_t)e0 * HH + t * 8);
#pragma unroll
                for (int k = 0; k < 8; k++) a[k] += w * (float)f[k];
            }
            for (int j = 64 + g; j < deg; j += 8) {
                int e0 = inc[s + j];
                bf16x8 f = *(const bf16x8*)(efc + (size_t)e0 * HH + t * 8);
#pragma unroll
                for (int k = 0; k < 8; k++) a[k] += (float)f[k];
            }
        }
#pragma unroll
        for (int k = 0; k < 8; k++) {
            a[k] += __shfl_xor(a[k], 8);
            a[k] += __shfl_xor(a[k], 16);
            a[k] += __shfl_xor(a[k], 32);
        }
        if (g == 0) {
            *(float4*)&aggl[vloc][t * 8]     = make_float4(a[0], a[1], a[2], a[3]);
            *(float4*)&aggl[vloc][t * 8 + 4] = make_float4(a[4], a[5], a[6], a[7]);
        }
    }
    __syncthreads();
    // phase 2: per-wave 16-edge tile
    int tile = blockIdx.x * 4 + wave;
    int r16 = lane & 15, hi = lane >> 4;
    int e = tile * 16 + r16;
    f32x4 acc[4] = {{0,0,0,0},{0,0,0,0},{0,0,0,0},{0,0,0,0}};
#pragma unroll
    for (int c = 0; c < 4; c++) {
        bf16x8 a;
        if (c < 2) {
            a = *(const bf16x8*)(efc + (size_t)e * HH + (c & 1) * 32 + hi * 8);
        } else {
            int vloc = (e >> 3) & 7;
            const float* p = &aggl[vloc][(c & 1) * 32 + hi * 8];
            a = cvt8(*(const float4*)p, *(const float4*)(p + 4));
        }
#pragma unroll
        for (int cb = 0; cb < 4; cb++) {
            bf16x8 b = load_bfrag(packw, layer, 14 + c, cb, lane);
            acc[cb] = __builtin_amdgcn_mfma_f32_16x16x32_bf16(a, b, acc[cb], 0, 0, 0);
        }
    }
#pragma unroll
    for (int cb = 0; cb < 4; cb++) {
        int col = cb * 16 + r16;
        float bias = be[layer * HH + col];
#pragma unroll
        for (int r = 0; r < 4; r++) {
            size_t ofs = (size_t)(tile * 16 + hi * 4 + r) * HH + col;
            float val = acc[cb][r] + bias;
            if (LAST) out32[ofs] = val;
            else      out16[ofs] = (__bf16)val;
        }
    }
}

extern "C" void kernel_launch(void* const* d_in, const int* in_sizes, int n_in,
                              void* d_out, int out_size, void* d_ws, size_t ws_size,
                              hipStream_t stream) {
    const float* x_in    = (const float*)d_in[0];
    const float* ef_in   = (const float*)d_in[1];
    const float* Wn_self = (const float*)d_in[2];
    const float* Wn_msg  = (const float*)d_in[3];
    const float* Wn_edge = (const float*)d_in[4];
    const float* bn      = (const float*)d_in[5];
    const float* Wfc     = (const float*)d_in[6];
    const float* bfc     = (const float*)d_in[7];
    const float* We_self = (const float*)d_in[8];
    const float* We_nbr  = (const float*)d_in[9];
    const float* be      = (const float*)d_in[10];
    const int*   trg     = (const int*)d_in[12];

    size_t off = 0;
    char* w = (char*)d_ws;
    auto alloc = [&](size_t bytes) -> char* {
        char* p = w + off;
        off += (bytes + 255) & ~(size_t)255;
        return p;
    };
    int*    count  = (int*)alloc((size_t)NN * 4);
    int*    offs   = (int*)alloc((size_t)(NN + 1) * 4);
    int*    cursor = (int*)alloc((size_t)NN * 4);
    int*    inc    = (int*)alloc((size_t)EE * 4);
    int*    btot   = (int*)alloc((size_t)NB * 4);
    int*    bbase  = (int*)alloc((size_t)NB * 4);
    __bf16* packw  = (__bf16*)alloc((size_t)3 * NCG * 4 * 64 * 8 * 2);
    float*  aggx   = (float*)alloc((size_t)NN * HH * 4);
    float*  agge   = (float*)alloc((size_t)NN * HH * 4);
    __bf16* xA     = (__bf16*)alloc((size_t)NN * HH * 2);
    __bf16* xB     = (__bf16*)alloc((size_t)NN * HH * 2);
    __bf16* ebA    = (__bf16*)alloc((size_t)EE * HH * 2);
    __bf16* ebB    = (__bf16*)alloc((size_t)EE * HH * 2);
    __bf16* efc16  = (__bf16*)alloc((size_t)EE * HH * 2);

    k_zero<<<(NN + 255) / 256, 256, 0, stream>>>(count);
    k_hist<<<(EE + 255) / 256, 256, 0, stream>>>(trg, count);
    k_bsum<<<NB, 256, 0, stream>>>(count, btot);
    k_bscan<<<1, 128, 0, stream>>>(btot, bbase);
    k_apply<<<NB, 256, 0, stream>>>(count, bbase, offs, cursor);
    k_fill<<<(EE + 255) / 256, 256, 0, stream>>>(trg, cursor, inc);
    k_pack<<<(3 * NCG * 4 * 64 * 8 + 255) / 256, 256, 0, stream>>>(
        Wn_self, Wn_msg, Wn_edge, Wfc, We_self, We_nbr, packw);

    const void*   xprev  = x_in;       // f32 for layer 0, bf16 after
    const __bf16* efprev = nullptr;    // layer 0 reads ef_in (f32) directly
    __bf16* xbuf[2] = {xA, xB};
    __bf16* ebuf[2] = {ebA, ebB};
    int ntile = (NN + 15) / 16;
    for (int i = 0; i < LL; i++) {
        if (i == 0)
            k_agg_node<true, true><<<NN / 4, 256, 0, stream>>>(xprev, ef_in, offs, inc,
                                                               aggx, agge);
        else
            k_agg_node<false, false><<<NN / 4, 256, 0, stream>>>(xprev, efprev, offs, inc,
                                                                 aggx, agge);
        __bf16* xnew = xbuf[i & 1];
        if (i == 0)
            k_node<true><<<(ntile + 3) / 4, 256, 0, stream>>>(xprev, aggx, agge, packw,
                                                              bn, xnew, i);
        else
            k_node<false><<<(ntile + 3) / 4, 256, 0, stream>>>(xprev, aggx, agge, packw,
                                                               bn, xnew, i);
        if (i == 0)
            k_fc<true><<<EE / 16 / 4, 256, 0, stream>>>(ef_in, xnew, trg, packw,
                                                        Wfc, bfc, efc16, i);
        else
            k_fc<false><<<EE / 16 / 4, 256, 0, stream>>>(efprev, xnew, trg, packw,
                                                         Wfc, bfc, efc16, i);
        __bf16* enext = ebuf[i & 1];
        if (i < LL - 1)
            k_edgeout<0><<<EE / 64, 256, 0, stream>>>(efc16, offs, inc, packw, be,
                                                      enext, (float*)d_out, i);
        else
            k_edgeout<1><<<EE / 64, 256, 0, stream>>>(efc16, offs, inc, packw, be,
                                                      enext, (float*)d_out, i);
        xprev = xnew;
        efprev = enext;
    }
}